// Round 10
// baseline (2925.881 us; speedup 1.0000x reference)
//
#include <hip/hip_runtime.h>

#define HH   100      // hidden
#define G4   400      // 4*H
#define BB   256      // batch
#define CC   9        // input channels
#define TT   1024     // timesteps
#define NCLS 6        // num classes
#define XSTR 13       // L1 transposed-x row stride
#define CH   64       // L2 chunk timesteps
#define NCH  (TT/CH)  // 16 chunks
#define TSTR 128      // L2 h1-tile row stride (floats)

__device__ __forceinline__ float sigm(float x) {
    return __fdividef(1.0f, 1.0f + __expf(-x));
}
__device__ __forceinline__ float tanh_fast(float x) {
    return 2.0f * sigm(2.0f * x) - 1.0f;
}
// wave-wide broadcast of lane l's value via readlane -> SGPR (no LDS pipe).
// REQUIRES: v computed by ALL 64 lanes of the wave (no divergence upstream).
__device__ __forceinline__ float bcast(float v, int l) {
    return __int_as_float(__builtin_amdgcn_readlane(__float_as_int(v), l));
}

// ---------------- Layer 1: x[B,C,T] -> h1[B,T,H] ----------------
// 512 threads, __launch_bounds__(512,2) -> proven 128-VGPR cap (R1).
// Waves 0-6: one gate row per thread (109 weights, fits). Wave 7 idles.
__global__ __launch_bounds__(512, 2)
void lstm_layer1(const float* __restrict__ x,     // [B,C,T]
                 const float* __restrict__ h0,    // [B,H]
                 const float* __restrict__ c0,    // [B,H]
                 const float* __restrict__ W_ih,  // [400,9]
                 const float* __restrict__ W_hh,  // [400,100]
                 const float* __restrict__ bias_g,// [400]
                 float* __restrict__ h1out)       // [B,T,H]
{
    const int b    = blockIdx.x;
    const int tid  = threadIdx.x;
    const int lane = tid & 63;

    __shared__ float xT[TT * XSTR + 64];   // transposed x: xT[t*13 + c]
    __shared__ float hb[128];              // h, padded + zeroed
    __shared__ float gates[448];

    const float* xb = x + (size_t)b * CC * TT;
    for (int i = tid; i < CC * TT; i += 512) {
        int c  = i >> 10;
        int tp = i & 1023;
        xT[tp * XSTR + c] = xb[i];
    }
    if (tid < 128) hb[tid] = (tid < HH) ? h0[b * HH + tid] : 0.0f;
    float c_reg = (tid < HH) ? c0[b * HH + tid] : 0.0f;

    const bool comp = (tid < 448);          // wave-uniform
    const int  row  = (tid < G4) ? tid : 0; // clamped duplicate rows

    float w[CC + HH], bg = 0.0f;
    if (comp) {
        #pragma unroll
        for (int j = 0; j < CC; ++j) w[j] = W_ih[row * CC + j];
        #pragma unroll
        for (int j = 0; j < HH; ++j) w[CC + j] = W_hh[row * HH + j];
        bg = bias_g[row];
        #pragma unroll
        for (int j = 0; j < CC + HH; ++j) asm volatile("" : "+v"(w[j]));
    }
    const bool isG = (row >= 2 * HH && row < 3 * HH);
    float* hout = h1out + (size_t)b * TT * HH;
    __syncthreads();

    #pragma unroll 1
    for (int t = 0; t < TT; ++t) {
        if (comp) {
            float vx = xT[t * XSTR + lane];
            float va = hb[lane];
            float vb = hb[64 + lane];       // broadcast only for j < 36
            asm volatile("" : "+v"(vx), "+v"(va), "+v"(vb));
            float a0 = bg, a1 = 0.f;
            #pragma unroll
            for (int c = 0; c < CC; ++c) {
                float h_ = bcast(vx, c);
                if (c & 1) a1 += h_ * w[c]; else a0 += h_ * w[c];
            }
            #pragma unroll
            for (int j = 0; j < 64; ++j) {
                float h_ = bcast(va, j);
                if (j & 1) a1 += h_ * w[CC + j]; else a0 += h_ * w[CC + j];
            }
            #pragma unroll
            for (int j = 0; j < 36; ++j) {
                float h_ = bcast(vb, j);
                if (j & 1) a1 += h_ * w[CC + 64 + j]; else a0 += h_ * w[CC + 64 + j];
            }
            gates[tid] = a0 + a1;           // rows 400-447 write unused dupes
        }
        __syncthreads();
        if (tid < HH) {
            float ri = gates[tid];
            float rf = gates[tid + HH];
            float rg = gates[tid + 2 * HH];
            float ro = gates[tid + 3 * HH];
            float cc = sigm(rf) * c_reg + sigm(ri) * tanh_fast(rg);
            c_reg = cc;
            float hv = sigm(ro) * tanh_fast(cc);
            hb[tid] = hv;
            hout[t * HH + tid] = hv;
        }
        __syncthreads();
    }
    (void)isG;
}

// -------- Layer 2 + final FC: h1[B,T,H] -> out[B,NC] --------
// 512 threads, __launch_bounds__(512,2). Per 64-step chunk:
//   phase A: wih[100] scoped-live, parallel over t, preS[t][row] = bg + wih.h1_t
//   phase B: whh[100] scoped-live, serial,          preS[t][row] += whh.h2
// Only one 100-float weight set live at a time -> fits the 128 cap.
__global__ __launch_bounds__(512, 2)
void lstm_layer2_fc(const float* __restrict__ h1,   // [B,T,H]
                    const float* __restrict__ h0,
                    const float* __restrict__ c0,
                    const float* __restrict__ W_ih, // [400,100]
                    const float* __restrict__ W_hh, // [400,100]
                    const float* __restrict__ bias_g,
                    const float* __restrict__ W_fc, // [6,100]
                    const float* __restrict__ b_fc, // [6]
                    float* __restrict__ out)        // [B,NC]
{
    const int b    = blockIdx.x;
    const int tid  = threadIdx.x;
    const int lane = tid & 63;

    __shared__ float tile[CH * TSTR];   // h1 chunk tile, 32 KB
    __shared__ float preS[CH * G4];     // pre-activations, 100 KB
    __shared__ float hb[128];           // h2 state, padded

    if (tid < 128) hb[tid] = (tid < HH) ? h0[b * HH + tid] : 0.0f;
    float c_reg = (tid < HH) ? c0[b * HH + tid] : 0.0f;

    const bool comp = (tid < 448);
    const int  row  = (tid < G4) ? tid : 0;
    const float bg  = comp ? bias_g[row] : 0.0f;

    const float* h1b = h1 + (size_t)b * TT * HH;
    __syncthreads();

    #pragma unroll 1
    for (int ch = 0; ch < NCH; ++ch) {
        const int t0 = ch * CH;
        // stage h1 tile: 64 rows x 25 float4 (coalesced)
        for (int i = tid; i < CH * 25; i += 512) {
            int r = i / 25;
            int c = i - r * 25;
            ((float4*)(tile + r * TSTR))[c] =
                ((const float4*)(h1b + (size_t)(t0 + r) * HH))[c];
        }
        __syncthreads();

        // ---- phase A: input projection (parallel over t, no barriers) ----
        {
            const float* wsrc = W_ih + (size_t)row * HH;
            asm volatile("" : "+v"(wsrc));      // opaque: no hoisting
            if (comp) {
                float wv[HH];
                #pragma unroll
                for (int j = 0; j < HH / 4; ++j)
                    *(float4*)&wv[4 * j] = ((const float4*)wsrc)[j];
                #pragma unroll
                for (int j = 0; j < HH; ++j) asm volatile("" : "+v"(wv[j]));
                #pragma unroll 1
                for (int t = 0; t < CH; ++t) {
                    float va = tile[t * TSTR + lane];
                    float vb = tile[t * TSTR + 64 + lane];   // j<36 used
                    asm volatile("" : "+v"(va), "+v"(vb));
                    float a0 = bg, a1 = 0.f;
                    #pragma unroll
                    for (int j = 0; j < 64; ++j) {
                        float h_ = bcast(va, j);
                        if (j & 1) a1 += h_ * wv[j]; else a0 += h_ * wv[j];
                    }
                    #pragma unroll
                    for (int j = 0; j < 36; ++j) {
                        float h_ = bcast(vb, j);
                        if (j & 1) a1 += h_ * wv[64 + j]; else a0 += h_ * wv[64 + j];
                    }
                    if (tid < G4) preS[t * G4 + row] = a0 + a1;
                }
            }
        }
        __syncthreads();

        // ---- phase B: recurrence ----
        {
            const float* wsrc = W_hh + (size_t)row * HH;
            asm volatile("" : "+v"(wsrc));      // opaque: no hoisting
            float wv[HH];
            if (comp) {
                #pragma unroll
                for (int j = 0; j < HH / 4; ++j)
                    *(float4*)&wv[4 * j] = ((const float4*)wsrc)[j];
                #pragma unroll
                for (int j = 0; j < HH; ++j) asm volatile("" : "+v"(wv[j]));
            }
            #pragma unroll 1
            for (int t = 0; t < CH; ++t) {
                if (comp) {
                    float va = hb[lane];
                    float vb = hb[64 + lane];               // j<36 used
                    asm volatile("" : "+v"(va), "+v"(vb));
                    float a0 = 0.f, a1 = 0.f;
                    #pragma unroll
                    for (int j = 0; j < 64; ++j) {
                        float h_ = bcast(va, j);
                        if (j & 1) a1 += h_ * wv[j]; else a0 += h_ * wv[j];
                    }
                    #pragma unroll
                    for (int j = 0; j < 36; ++j) {
                        float h_ = bcast(vb, j);
                        if (j & 1) a1 += h_ * wv[64 + j]; else a0 += h_ * wv[64 + j];
                    }
                    if (tid < G4) preS[t * G4 + row] += a0 + a1;
                }
                __syncthreads();
                if (tid < HH) {
                    float ri = preS[t * G4 + tid];
                    float rf = preS[t * G4 + HH + tid];
                    float rg = preS[t * G4 + 2 * HH + tid];
                    float ro = preS[t * G4 + 3 * HH + tid];
                    float cc = sigm(rf) * c_reg + sigm(ri) * tanh_fast(rg);
                    c_reg = cc;
                    hb[tid] = sigm(ro) * tanh_fast(cc);
                }
                __syncthreads();
            }
        }
    }

    // final FC on h2 at t = T-1
    if (tid < NCLS) {
        float acc = b_fc[tid];
        #pragma unroll 4
        for (int j = 0; j < HH; ++j) acc += W_fc[tid * HH + j] * hb[j];
        out[b * NCLS + tid] = acc;
    }
}

extern "C" void kernel_launch(void* const* d_in, const int* in_sizes, int n_in,
                              void* d_out, int out_size, void* d_ws, size_t ws_size,
                              hipStream_t stream) {
    const float* x     = (const float*)d_in[0];
    const float* h0_1  = (const float*)d_in[1];
    const float* c0_1  = (const float*)d_in[2];
    const float* h0_2  = (const float*)d_in[3];
    const float* c0_2  = (const float*)d_in[4];
    const float* W_ih1 = (const float*)d_in[5];
    const float* W_hh1 = (const float*)d_in[6];
    const float* b1    = (const float*)d_in[7];
    const float* W_ih2 = (const float*)d_in[8];
    const float* W_hh2 = (const float*)d_in[9];
    const float* b2    = (const float*)d_in[10];
    const float* W_fc  = (const float*)d_in[11];
    const float* b_fc  = (const float*)d_in[12];
    float* out = (float*)d_out;

    float* h1 = (float*)d_ws;   // [B,T,H] fp32 = 104.8 MB

    lstm_layer1<<<BB, 512, 0, stream>>>(x, h0_1, c0_1, W_ih1, W_hh1, b1, h1);
    lstm_layer2_fc<<<BB, 512, 0, stream>>>(h1, h0_2, c0_2, W_ih2, W_hh2, b2,
                                           W_fc, b_fc, out);
}